// Round 1
// baseline (389.204 us; speedup 1.0000x reference)
//
#include <hip/hip_runtime.h>
#include <hip/hip_bf16.h>

// HGNN_conv: the reference's floor(softmax/1000) term is identically zero
// (softmax in (0,1], /1000 < 1, floor -> 0), so e == G exactly and
//   out = G @ (x @ weight + bias).
// G has exactly K=5 ones per row at columns qq[5i..5i+4], so
//   out[i,f] = sum_k E[qq[5i+k], f] + 5*bias[f],  E = x @ weight.
// This skips the 327 MB dense G read entirely.

#define IN_FT 256
#define OUT_FT 64
#define KCARD 5
#define RPB 32   // rows of x per block in the GEMM

__global__ __launch_bounds__(256) void gemm_xw(const float* __restrict__ x,
                                               const float* __restrict__ w,
                                               float* __restrict__ e,
                                               int n2) {
    __shared__ float xs[RPB][IN_FT];
    const int tid = threadIdx.x;
    const int row0 = blockIdx.x * RPB;

    // Stage a 32x256 tile of x into LDS (float4, coalesced).
    // RPB*IN_FT/4 = 2048 float4 slots / 256 threads = 8 per thread.
    #pragma unroll
    for (int j = 0; j < (RPB * IN_FT / 4) / 256; ++j) {
        int fidx = tid + j * 256;          // float4 index within the tile
        int r    = fidx / (IN_FT / 4);
        int c4   = fidx % (IN_FT / 4);
        float4 v = make_float4(0.f, 0.f, 0.f, 0.f);
        if (row0 + r < n2)
            v = ((const float4*)(x + (size_t)(row0 + r) * IN_FT))[c4];
        ((float4*)&xs[r][0])[c4] = v;
    }
    __syncthreads();

    const int col = tid & 63;   // output feature
    const int rg  = tid >> 6;   // row group: 8 rows each

    float acc[8] = {0.f, 0.f, 0.f, 0.f, 0.f, 0.f, 0.f, 0.f};

    for (int c = 0; c < IN_FT; c += 4) {
        // weight reads: lane `col` -> consecutive addresses, coalesced; L2-hot.
        float w0 = w[(c + 0) * OUT_FT + col];
        float w1 = w[(c + 1) * OUT_FT + col];
        float w2 = w[(c + 2) * OUT_FT + col];
        float w3 = w[(c + 3) * OUT_FT + col];
        #pragma unroll
        for (int rr = 0; rr < 8; ++rr) {
            // wave-uniform LDS address -> broadcast, conflict-free
            float4 xv = ((const float4*)&xs[rg * 8 + rr][0])[c / 4];
            acc[rr] += xv.x * w0 + xv.y * w1 + xv.z * w2 + xv.w * w3;
        }
    }

    #pragma unroll
    for (int rr = 0; rr < 8; ++rr) {
        int r = row0 + rg * 8 + rr;
        if (r < n2) e[(size_t)r * OUT_FT + col] = acc[rr];
    }
}

__global__ __launch_bounds__(256) void gather_sum(const float* __restrict__ e,
                                                  const int* __restrict__ qq,
                                                  const float* __restrict__ bias,
                                                  float* __restrict__ out,
                                                  int n1) {
    const int tid = threadIdx.x;
    const int row = blockIdx.x * 4 + (tid >> 6);
    const int f   = tid & 63;
    if (row >= n1) return;

    float s = bias[f] * (float)KCARD;
    #pragma unroll
    for (int k = 0; k < KCARD; ++k) {
        int q = qq[row * KCARD + k];          // wave-uniform -> scalar load
        s += e[(size_t)q * OUT_FT + f];       // 64 consecutive floats, coalesced
    }
    out[(size_t)row * OUT_FT + f] = s;
}

extern "C" void kernel_launch(void* const* d_in, const int* in_sizes, int n_in,
                              void* d_out, int out_size, void* d_ws, size_t ws_size,
                              hipStream_t stream) {
    // inputs: 0=x [N2*256], 1=G (unused), 2=weight [256*64], 3=a (unused),
    //         4=bias [64], 5=qq [N1*5], 6=rows (unused)
    const float* x    = (const float*)d_in[0];
    const float* w    = (const float*)d_in[2];
    const float* bias = (const float*)d_in[4];
    const int*   qq   = (const int*)d_in[5];
    float* out = (float*)d_out;
    float* e   = (float*)d_ws;               // [n2, OUT_FT] scratch

    const int n2 = in_sizes[0] / IN_FT;      // 10000
    const int n1 = out_size / OUT_FT;        // 8192

    dim3 gblk((n2 + RPB - 1) / RPB);         // 313 blocks
    gemm_xw<<<gblk, 256, 0, stream>>>(x, w, e, n2);

    dim3 sblk((n1 + 3) / 4);                 // 2048 blocks
    gather_sum<<<sblk, 256, 0, stream>>>(e, qq, bias, out, n1);
}